// Round 6
// baseline (71.180 us; speedup 1.0000x reference)
//
#include <hip/hip_runtime.h>

#define L_LEAVES 8192
#define W_LAMBDA 2101
#define WPAD     2104              // padded table stride (16B-aligned rows)
#define SA2_40   0.41317591116653485f
#define LOG2E_F  1.4426950408889634f
#define LN2_F    0.6931471805599453f

__device__ __forceinline__ float rcpf(float x)  { return __builtin_amdgcn_rcpf(x); }
__device__ __forceinline__ float log2f_fast(float x) { return __builtin_amdgcn_logf(x); }   // v_log_f32 = log2
__device__ __forceinline__ float exp2f_fast(float x) { return __builtin_amdgcn_exp2f(x); }  // v_exp_f32 = 2^x
__device__ __forceinline__ float sqrtf_fast(float x) { return __builtin_amdgcn_sqrtf(x); }

// ---- transmissivity of a dielectric plane (Stern / Allen), per-wavelength ----
__device__ __forceinline__ float getav_dev(float sa2, bool is90, float nr) {
    float n2  = nr * nr;
    float npx = n2 + 1.0f;
    float nm  = n2 - 1.0f;
    float a   = (nr + 1.0f) * (nr + 1.0f) * 0.5f;
    float k   = -(n2 - 1.0f) * (n2 - 1.0f) * 0.25f;
    float b2  = sa2 - npx * 0.5f;
    float b1  = is90 ? 0.0f : sqrtf(b2 * b2 + k);
    float b   = b1 - b2;
    float k2  = k * k;
    float b3  = b * b * b;
    float a3  = a * a * a;
    float ts  = k2 / (6.0f * b3) + k / b - b * 0.5f
              - (k2 / (6.0f * a3) + k / a - a * 0.5f);
    float tp1 = -2.0f * n2 * (b - a) / (npx * npx);
    float nm2 = nm * nm;
    float tp2 = -2.0f * n2 * npx * logf(b / a) / nm2;
    float tp3 = n2 * (1.0f / b - 1.0f / a) * 0.5f;
    float n22 = n2 * n2;
    float npx3 = npx * npx * npx;
    float npax_a = 2.0f * npx * a - nm2;
    float npx_b  = 2.0f * npx * b - nm2;
    float tp4 = 16.0f * n22 * (n22 + 1.0f) * logf(npx_b / npax_a) / (npx3 * nm2);
    float tp5 = 16.0f * n2 * n2 * n2 * (1.0f / npx_b - 1.0f / npax_a) / npx3;
    float tp  = tp1 + tp2 + tp3 + tp4 + tp5;
    return (ts + tp) / (2.0f * sa2);
}

// per-wavelength table rows: 0: talf*t21  1: ralf  2: t12*t21  3: r12  4: r21
__global__ void precompute_kernel(const float* __restrict__ nr, float* __restrict__ tab) {
    int w = blockIdx.x * blockDim.x + threadIdx.x;
    if (w >= W_LAMBDA) return;
    float n    = nr[w];
    float talf = getav_dev(SA2_40, false, n);
    float t12  = getav_dev(1.0f,   true,  n);
    float t21  = t12 * rcpf(n * n);
    float r21  = 1.0f - t21;
    tab[0 * WPAD + w] = talf * t21;
    tab[1 * WPAD + w] = 1.0f - talf;
    tab[2 * WPAD + w] = t12 * t21;
    tab[3 * WPAD + w] = 1.0f - t12;
    tab[4 * WPAD + w] = r21;
}

template<bool USE_TAB>
__global__ __launch_bounds__(128) void prospect_kernel(
    const float* __restrict__ pN,   const float* __restrict__ pcab,
    const float* __restrict__ pcar, const float* __restrict__ pwater,
    const float* __restrict__ plma, const float* __restrict__ pcant,
    const float* __restrict__ pnr,
    const float* __restrict__ pkab, const float* __restrict__ pkcar,
    const float* __restrict__ pkant, const float* __restrict__ pkw,
    const float* __restrict__ pkm,
    const float* __restrict__ tab,
    float* __restrict__ out_r, float* __restrict__ out_t)
{
    const int pr = blockIdx.x * 128 + threadIdx.x;   // wavelength-pair id
    const int w0 = pr * 2;
    if (w0 >= W_LAMBDA) return;
    const bool full = (w0 + 2 <= W_LAMBDA);

    const int l = blockIdx.y;                        // uniform -> s_load traits
    const float Nl   = pN[l];
    const float invN = rcpf(Nl);
    const float Nm1  = Nl - 1.0f;
    const float cabl = pcab[l] * invN, carl = pcar[l] * invN, cantl = pcant[l] * invN;
    const float watl = pwater[l] * invN, lmal = plma[l] * invN;

    // per-wavelength pair data (8B-aligned: w0 even, WPAD even)
    float2 vkab, vkcar, vkant, vkw, vkm;
    float2 t0, t1, t2, t3, t4;
    if (full) {
        vkab  = *(const float2*)(pkab  + w0);
        vkcar = *(const float2*)(pkcar + w0);
        vkant = *(const float2*)(pkant + w0);
        vkw   = *(const float2*)(pkw   + w0);
        vkm   = *(const float2*)(pkm   + w0);
    } else {
        vkab.x = vkab.y = pkab[w0];
        vkcar.x = vkcar.y = pkcar[w0];
        vkant.x = vkant.y = pkant[w0];
        vkw.x = vkw.y = pkw[w0];
        vkm.x = vkm.y = pkm[w0];
    }
    if (USE_TAB) {
        if (full) {
            t0 = *(const float2*)(tab + 0 * WPAD + w0);
            t1 = *(const float2*)(tab + 1 * WPAD + w0);
            t2 = *(const float2*)(tab + 2 * WPAD + w0);
            t3 = *(const float2*)(tab + 3 * WPAD + w0);
            t4 = *(const float2*)(tab + 4 * WPAD + w0);
        } else {
            t0.x = t0.y = tab[0 * WPAD + w0];
            t1.x = t1.y = tab[1 * WPAD + w0];
            t2.x = t2.y = tab[2 * WPAD + w0];
            t3.x = t3.y = tab[3 * WPAD + w0];
            t4.x = t4.y = tab[4 * WPAD + w0];
        }
    } else {
        #pragma unroll
        for (int jj = 0; jj < 2; ++jj) {
            int w = min(w0 + jj, W_LAMBDA - 1);
            float n    = pnr[w];
            float talf = getav_dev(SA2_40, false, n);
            float t12  = getav_dev(1.0f,   true,  n);
            float t21  = t12 * rcpf(n * n);
            float r21  = 1.0f - t21;
            ((float*)&t0)[jj] = talf * t21;
            ((float*)&t1)[jj] = 1.0f - talf;
            ((float*)&t2)[jj] = t12 * t21;
            ((float*)&t3)[jj] = 1.0f - t12;
            ((float*)&t4)[jj] = r21;
        }
    }

    float rf[2], tr[2];
    #pragma unroll
    for (int jj = 0; jj < 2; ++jj) {
        const float c0 = ((const float*)&t0)[jj], c1 = ((const float*)&t1)[jj];
        const float c2 = ((const float*)&t2)[jj], c3 = ((const float*)&t3)[jj];
        const float c4 = ((const float*)&t4)[jj];

        // absorption coefficient (traits pre-divided by N)
        float k = fmaf(cabl, ((const float*)&vkab)[jj],
                  fmaf(carl, ((const float*)&vkcar)[jj],
                  fmaf(cantl, ((const float*)&vkant)[jj],
                  fmaf(watl, ((const float*)&vkw)[jj],
                       lmal * ((const float*)&vkm)[jj]))));
        k = fmaxf(k, 1e-4f);

        // tau = (1-k)e^{-k} + k^2 E1(k)
        float ek   = exp2f_fast(-k * LOG2E_F);
        float lg2k = log2f_fast(k);
        float poly = fmaf(fmaf(fmaf(fmaf(fmaf(0.00107857f, k, -0.00976004f), k, 0.05519968f),
                        k, -0.24991055f), k, 0.99999193f), k, -0.57721566f);
        float e1s  = fmaf(-LN2_F, lg2k, poly);
        float taus = fmaf(k * k, e1s, fmaf(-k, ek, ek));     // (1-k)ek + k^2 e1s
        float pn = fmaf(fmaf(fmaf(k + 8.5733287401f, k, 18.0590169730f),
                       k, 8.6347608925f), k, 0.2677737343f);
        float pd = fmaf(fmaf(fmaf(k + 9.5733223454f, k, 25.6329561486f),
                       k, 21.0996530827f), k, 3.9584969228f);
        float taub = ek * fmaf(k, pn - pd, pd) * rcpf(pd);   // ek*(pd+k(pn-pd))/pd
        float tau  = (k <= 1.0f) ? taus : taub;

        // one-layer R/T; denom from (r21*tau)^2 — no table row needed
        float r21t = c4 * tau;
        float rd   = rcpf(fmaf(-r21t, r21t, 1.0f));  // 1/(1 - r21^2 tau^2)
        float trd  = tau * rd;
        float Ta   = c0 * trd;                       // talf*t21 * tau / denom
        float tt   = c2 * trd;                       // t12*t21  * tau / denom
        float Ra   = fmaf(r21t, Ta, c1);
        float rr   = fmaf(r21t, tt, c3);

        // Stokes N-1 layers (den2*den3 merged into M)
        float rpt  = rr + tt;
        float rmt  = rr - tt;
        bool  mask = (rpt >= 1.0f);
        float Dsq  = fmaf(-rmt, rmt, 1.0f) * fmaf(-rpt, rpt, 1.0f);
        float D    = sqrtf_fast(mask ? 1.0f : Dsq);
        float rq   = rpt * rmt;                      // r^2 - t^2
        float s1   = 1.0f + D;
        float rp2  = rcpf((rr * tt) * 4.0f);         // pair-reciprocal 1/(2r),1/(2t)
        float aa   = (s1 + rq) * (rp2 * (tt + tt));
        float bb   = (s1 - rq) * (rp2 * (rr + rr));
        float bsafe = mask ? 1.0f : bb;
        float bnm1 = exp2f_fast(Nm1 * log2f_fast(bsafe));   // b^(N-1)
        float bn2  = bnm1 * bnm1;
        float a2   = aa * aa;
        float den2 = fmaf(a2, bn2, -1.0f);           // a^2 b^{2n} - 1
        float bn2m1 = bn2 - 1.0f;
        float M    = fmaf(-aa * rr, bn2m1, den2);    // den2 - a r (b^{2n}-1) = den2*den3
        float invM = rcpf(M);
        float TaM  = Ta * invM;
        float tranj = TaM * bnm1 * (a2 - 1.0f);      // Ta*Tsub/den3
        float reflj = fmaf(TaM * tt * aa, bn2m1, Ra);// Ra + Ta*Rsub*t/den3

        if (__any((int)mask)) {                      // thick-leaf branch (rare)
            float Talt = tt * rcpf(fmaf(Nm1, 1.0f - tt, tt));
            float Rsm  = 1.0f - Talt;
            float g    = Ta * rcpf(fmaf(-Rsm, rr, 1.0f));
            if (mask) { tranj = g * Talt; reflj = fmaf(g * Rsm, tt, Ra); }
        }

        tr[jj] = tranj;
        rf[jj] = reflj;
    }

    const unsigned base = (unsigned)l * W_LAMBDA + w0;
    out_r[base] = rf[0];
    out_t[base] = tr[0];
    if (full) {
        out_r[base + 1] = rf[1];
        out_t[base + 1] = tr[1];
    }
}

extern "C" void kernel_launch(void* const* d_in, const int* in_sizes, int n_in,
                              void* d_out, int out_size, void* d_ws, size_t ws_size,
                              hipStream_t stream) {
    const float* pN     = (const float*)d_in[0];
    const float* pcab   = (const float*)d_in[1];
    const float* pcar   = (const float*)d_in[2];
    const float* pwater = (const float*)d_in[3];
    const float* plma   = (const float*)d_in[4];
    const float* pcant  = (const float*)d_in[5];
    const float* pnr    = (const float*)d_in[6];
    const float* pkab   = (const float*)d_in[7];
    const float* pkcar  = (const float*)d_in[8];
    const float* pkant  = (const float*)d_in[9];
    const float* pkw    = (const float*)d_in[10];
    const float* pkm    = (const float*)d_in[11];
    float* out_r = (float*)d_out;
    float* out_t = out_r + (size_t)L_LEAVES * W_LAMBDA;

    const int npairs = (W_LAMBDA + 1) / 2;                 // 1051
    dim3 grid((npairs + 127) / 128, L_LEAVES);             // (9, 8192)
    dim3 block(128);

    const size_t tab_bytes = 5 * WPAD * sizeof(float);
    if (ws_size >= tab_bytes) {
        float* tabp = (float*)d_ws;
        precompute_kernel<<<(W_LAMBDA + 255) / 256, 256, 0, stream>>>(pnr, tabp);
        prospect_kernel<true><<<grid, block, 0, stream>>>(
            pN, pcab, pcar, pwater, plma, pcant, pnr,
            pkab, pkcar, pkant, pkw, pkm, (const float*)tabp, out_r, out_t);
    } else {
        prospect_kernel<false><<<grid, block, 0, stream>>>(
            pN, pcab, pcar, pwater, plma, pcant, pnr,
            pkab, pkcar, pkant, pkw, pkm, nullptr, out_r, out_t);
    }
}